// Round 21
// baseline (200.863 us; speedup 1.0000x reference)
//
#include <hip/hip_runtime.h>

// ---------------------------------------------------------------------------
// MalConv fused: GEMM M=16000, K=4000, N=256 (W1||W2 col-interleaved) in bf16
// MFMA 16x16x32, lane-local GLU+relu+segmented-max epilogue, then tiny FC.
//
// Round-23 == round-20 unchanged (infra failure; 4-wave TLP split still
// unbenchmarked). r17 post-mortem: zero-copy 3-phase pipeline measured
// 90.8us / VGPR=120 / MfmaUtil 14% == rotation loop (94us). The register
// allocator sinks loads toward uses, collapsing the SW pipeline; at 1
// wave/SIMD there is no TLP to cover the ~1700cyc/phase latency chain.
// Fix: split each 64x64 tile across 4 waves (2M x 2N), 256-thr blocks:
//  * wave (wm,wn): rows m0+wm*32..+31, interleaved cols nq*64+wn*32..+31.
//    acc[2][2] (+3 A/B/x sets) ~ 95 VGPR -> __launch_bounds__(256,4) ->
//    16 waves/CU = 4 waves/SIMD of TLP.
//  * N-split is free: a 32-col interleaved group = 16 W1 + 16 paired W2 cols,
//    so GLU stays lane-local per wave (g1=acc[mi][0], g2=acc[mi][1]);
//    NO inter-wave reduction, no barriers after the embb fill.
//  * M-split doubles B L2 traffic (500MB -> 1GB ~ 29us L2 floor) — accepted;
//    x/embb shared in-block via L1/L2/LDS.
//  * Per-wave K-loop unchanged: zero-copy 3-phase sets, full K=125,
//    41 triples + 2-phase MFMA tail, clamped indices.
//  * Unchanged (HW-verified r13/r17, absmax 0.03125): interleaved Bblk pack,
//    XCD-chunked remap, segmented-max epilogue, atomicMax m_ws, tiny fc.
// ---------------------------------------------------------------------------

typedef __attribute__((ext_vector_type(8))) short short8;
typedef __attribute__((ext_vector_type(4))) float f32x4;

__device__ __forceinline__ unsigned short f2b(float f) {
    union { float f; unsigned u; } un;
    un.f = f;
    unsigned u = un.u;
    return (unsigned short)((u + 0x7FFFu + ((u >> 16) & 1u)) >> 16);  // RNE
}

#define KT_COUNT 125                              // K = 4000 = 125 * 32
#define WS_BBLK_BYTES (KT_COUNT * 256 * 32 * 2)   // 2,048,000 B bf16 weights
#define WS_MWS_OFF WS_BBLK_BYTES                  // 8*128 f32 max accumulator

// Pack W1,W2 (fp32 [128][8][500]) -> bf16 Bblk[kt][c][g*8+ch] with
// INTERLEAVED columns: c = grp*32 + s; s<16 -> W1[grp*16+s], s>=16 ->
// W2[grp*16+s-16]. (kt,g) -> k = kt*4+g. One uint4 per thread, coalesced
// writes. Also zero-inits the m_ws max accumulator.
__global__ __launch_bounds__(256) void prep_weights(
        const float* __restrict__ W1, const float* __restrict__ W2,
        unsigned short* __restrict__ Bblk, float* __restrict__ m_ws) {
    int u   = blockIdx.x * 256 + threadIdx.x;     // 0 .. 127,999 (uint4 idx)
    int kt  = u >> 10;                            // /1024
    int rem = u & 1023;
    int c   = rem >> 2;                           // interleaved col 0..255
    int g   = rem & 3;
    int k   = kt * 4 + g;                         // 0..499
    int grp = c >> 5, s = c & 31;
    const float* W = (s < 16) ? W1 : W2;
    int oo = grp * 16 + (s & 15);                 // 0..127
    unsigned short v[8];
#pragma unroll
    for (int ch = 0; ch < 8; ++ch) v[ch] = f2b(W[oo * 4000 + ch * 500 + k]);
    uint4 pack;
    pack.x = (unsigned)v[0] | ((unsigned)v[1] << 16);
    pack.y = (unsigned)v[2] | ((unsigned)v[3] << 16);
    pack.z = (unsigned)v[4] | ((unsigned)v[5] << 16);
    pack.w = (unsigned)v[6] | ((unsigned)v[7] << 16);
    *(uint4*)&Bblk[u * 8] = pack;
    if (blockIdx.x < 4) m_ws[blockIdx.x * 256 + threadIdx.x] = 0.f;
}

// Main fused kernel: 1000 blocks x 256 threads (4 waves). Block = tile
// (mt, nq): rows mt*64..+63, interleaved cols nq*64..+63. Wave wv:
// wm = wv>>1 (m half), wn = wv&1 (32-col group).
__global__ __launch_bounds__(256, 4) void malconv_main(
        const int* __restrict__ x, const float* __restrict__ emb,
        const float* __restrict__ b1, const float* __restrict__ b2,
        const unsigned short* __restrict__ Bblk, float* __restrict__ m_ws) {
    __shared__ __align__(16) unsigned short embb[257 * 8];     // bf16 emb rows

    const int t = threadIdx.x;
    for (int e = t; e < 257 * 8; e += 256) embb[e] = f2b(emb[e]);

    // XCD-chunked remap: the 4 nq blocks of an m-tile are 8 apart in
    // blockIdx -> same XCD under round-robin dispatch -> x/Bblk L2 reuse.
    const int w  = (blockIdx.x & 7) * 125 + (blockIdx.x >> 3);
    const int mt = w >> 2, nq = w & 3;
    const int m0 = mt * 64;

    const int lane = t & 63, wv = t >> 6;
    const int wm = wv >> 1, wn = wv & 1;
    const int quad = lane >> 4, l16 = lane & 15;

    // B fragment base: interleaved col = nq*64 + wn*32 + ni*16 + l16,
    // 32 shorts/col per kt, k-group = quad. ni stride = 512 shorts.
    const unsigned short* bbase =
        Bblk + (nq * 64 + wn * 32 + l16) * 32 + quad * 8;

    // per-lane x pointers: row m0 + wm*32 + mi*16 + l16, pos kt*4 + quad.
    const int* xr = x + (m0 + wm * 32 + l16) * 500 + quad;  // + mi*8000

    f32x4 acc[2][2];
#pragma unroll
    for (int mi = 0; mi < 2; ++mi)
#pragma unroll
        for (int ni = 0; ni < 2; ++ni) {
            f32x4 z = {0.f, 0.f, 0.f, 0.f};
            acc[mi][ni] = z;
        }

    __syncthreads();  // embb ready (the only block-wide barrier)

    // ---- zero-copy 3-phase pipeline state (per wave) ----
    short8 a0[2], a1[2], a2[2];
    short8 q0[2], q1[2], q2[2];
    int    x0[2], x1[2], x2[2];

#pragma unroll
    for (int mi = 0; mi < 2; ++mi) {
        int v0 = xr[mi * 8000 + 0];
        int v1 = xr[mi * 8000 + 4];
        int v2 = xr[mi * 8000 + 8];
        a0[mi] = *(const short8*)&embb[v0 * 8];
        a1[mi] = *(const short8*)&embb[v1 * 8];
        a2[mi] = *(const short8*)&embb[v2 * 8];
        x0[mi] = xr[mi * 8000 + 12];              // x@3
        x1[mi] = xr[mi * 8000 + 16];              // x@4
        x2[mi] = xr[mi * 8000 + 20];              // x@5
    }
#pragma unroll
    for (int ni = 0; ni < 2; ++ni) {
        q0[ni] = *(const short8*)(bbase + 0 * 8192 + ni * 512);
        q1[ni] = *(const short8*)(bbase + 1 * 8192 + ni * 512);
        q2[ni] = *(const short8*)(bbase + 2 * 8192 + ni * 512);
    }

    // Phase: consume (A,B) for kt, refill the SAME registers for kt+3.
    auto phase = [&](short8 (&A)[2], short8 (&B)[2], int (&X)[2], int kt) {
#pragma unroll
        for (int mi = 0; mi < 2; ++mi)
#pragma unroll
            for (int ni = 0; ni < 2; ++ni)
                acc[mi][ni] = __builtin_amdgcn_mfma_f32_16x16x32_bf16(
                    A[mi], B[ni], acc[mi][ni], 0, 0, 0);
        const int ktn = (kt + 3 < KT_COUNT) ? kt + 3 : KT_COUNT - 1;
#pragma unroll
        for (int ni = 0; ni < 2; ++ni)
            B[ni] = *(const short8*)(bbase + ktn * 8192 + ni * 512);
#pragma unroll
        for (int mi = 0; mi < 2; ++mi)
            A[mi] = *(const short8*)&embb[X[mi] * 8];
        const int ktx = (kt + 6 < KT_COUNT) ? kt + 6 : KT_COUNT - 1;
#pragma unroll
        for (int mi = 0; mi < 2; ++mi)
            X[mi] = xr[mi * 8000 + ktx * 4];
    };

    // 41 triples cover kt = 0..122; tail handles 123, 124.
    for (int ktb = 0; ktb < 123; ktb += 3) {
        phase(a0, q0, x0, ktb);
        phase(a1, q1, x1, ktb + 1);
        phase(a2, q2, x2, ktb + 2);
    }
#pragma unroll
    for (int mi = 0; mi < 2; ++mi)
#pragma unroll
        for (int ni = 0; ni < 2; ++ni)
            acc[mi][ni] = __builtin_amdgcn_mfma_f32_16x16x32_bf16(
                a0[mi], q0[ni], acc[mi][ni], 0, 0, 0);
#pragma unroll
    for (int mi = 0; mi < 2; ++mi)
#pragma unroll
        for (int ni = 0; ni < 2; ++ni)
            acc[mi][ni] = __builtin_amdgcn_mfma_f32_16x16x32_bf16(
                a1[mi], q1[ni], acc[mi][ni], 0, 0, 0);

    // ---- wave-local epilogue: GLU + relu + segmented max ----
    // g1 = acc[mi][0] (W1 out j), g2 = acc[mi][1] (W2 out j),
    // j = (nq*2 + wn)*16 + l16. Rows rbase + mi*16 + quad*4 + r.
    const int j = (nq * 2 + wn) * 16 + l16;
    const float bb1 = b1[j], bb2 = b2[j];
    const int rbase = m0 + wm * 32;
    const int b0i = rbase / 2000;
    const int bsplit = (b0i + 1) * 2000;          // first patch of next batch
    const bool crosses = (rbase + 31) >= bsplit;
    float mx0 = 0.f, mx1 = 0.f;                   // h >= 0 always
#pragma unroll
    for (int mi = 0; mi < 2; ++mi)
#pragma unroll
        for (int r = 0; r < 4; ++r) {
            int row = rbase + mi * 16 + quad * 4 + r;
            float g1 = acc[mi][0][r] + bb1;
            float g2 = acc[mi][1][r] + bb2;
            float h = fmaxf(g1 / (1.f + __expf(-g2)), 0.f);
            if (row >= bsplit) mx1 = fmaxf(mx1, h);
            else               mx0 = fmaxf(mx0, h);
        }
    // reduce over quad (lanes with same l16)
    mx0 = fmaxf(mx0, __shfl_xor(mx0, 16));
    mx0 = fmaxf(mx0, __shfl_xor(mx0, 32));
    mx1 = fmaxf(mx1, __shfl_xor(mx1, 16));
    mx1 = fmaxf(mx1, __shfl_xor(mx1, 32));
    if (quad == 0) {
        // nonneg floats: int compare == float compare
        atomicMax((int*)&m_ws[b0i * 128 + j], __float_as_int(mx0));
        if (crosses)
            atomicMax((int*)&m_ws[(b0i + 1) * 128 + j], __float_as_int(mx1));
    }
}

// out[b][j] = sum_o m_ws[b][o] * fcW[j][o] + fcb[j]   (16 outputs)
__global__ void fc_kernel(const float* __restrict__ m_ws,
                          const float* __restrict__ fcW,
                          const float* __restrict__ fcb,
                          float* __restrict__ out) {
    int t = threadIdx.x;
    if (t < 16) {
        int b = t >> 1, j = t & 1;
        float s = 0.f;
        for (int o = 0; o < 128; ++o) s += m_ws[b * 128 + o] * fcW[j * 128 + o];
        out[t] = s + fcb[j];
    }
}

extern "C" void kernel_launch(void* const* d_in, const int* in_sizes, int n_in,
                              void* d_out, int out_size, void* d_ws, size_t ws_size,
                              hipStream_t stream) {
    const int*   x   = (const int*)d_in[0];     // [8, 1e6] values 0..256
    const float* emb = (const float*)d_in[1];   // [257, 8]
    const float* W1  = (const float*)d_in[2];   // [128, 8, 500]
    const float* b1  = (const float*)d_in[3];   // [128]
    const float* W2  = (const float*)d_in[4];   // [128, 8, 500]
    const float* b2  = (const float*)d_in[5];   // [128]
    const float* fcW = (const float*)d_in[6];   // [2, 128]
    const float* fcb = (const float*)d_in[7];   // [2]
    float* out = (float*)d_out;                 // [8, 2]

    unsigned short* Bblk = (unsigned short*)d_ws;
    float* m_ws = (float*)((char*)d_ws + WS_MWS_OFF);

    prep_weights<<<500, 256, 0, stream>>>(W1, W2, Bblk, m_ws);
    malconv_main<<<1000, 256, 0, stream>>>(x, emb, b1, b2, Bblk, m_ws);
    fc_kernel<<<1, 64, 0, stream>>>(m_ws, fcW, fcb, out);
}

// Round 22
// 171.870 us; speedup vs baseline: 1.1687x; 1.1687x over previous
//
#include <hip/hip_runtime.h>

// ---------------------------------------------------------------------------
// MalConv fused: GEMM M=16000, K=4000, N=256 (W1||W2 col-interleaved) in bf16
// MFMA 16x16x32, lane-local GLU+relu+segmented-max epilogue, then tiny FC.
//
// Round-24 = r17 shape (1000x64, 64x64/wave, 16-MFMA ILP) + UNSINKABLE x
// prefetch via global_load_lds super-phase staging.
//  * r20 post-mortem: 4-wave TLP split REGRESSED (90.8 -> 130us, VGPR=48,
//    conflicts 2x) — duplication doubled traffic, ILP/4, TLP didn't pay.
//  * Revised theory: common ~90-130us across all 3 structures = exposed
//    COLD-HBM x-load latency (~900cyc, x=32MB read once) per phase; register
//    prefetch gets sunk by the allocator (VGPR 120/48 measured).
//  * Fix: x staged in LDS xs[2][32pos][64rows] per 8-kt super-phase with 32
//    global_load_lds (width 4, per-lane gather source, lane-linear dest) —
//    async, NO dest register -> unsinkable; issued ~2500cyc ahead; ONE
//    syncthreads per 8 kt drains (16 barriers total, m97 pattern).
//  * Per-kt chain: xs ds_read_b32 -> embb gather b128 -> 16 MFMA; B zero-copy
//    even/odd 2-phase register prefetch (bA/bB).
//  * prep_weights: float4 W reads (4x fewer line-touches), coalesced writes.
//  * Unchanged (HW-verified r13/r17/r20, absmax 0.03125): interleaved Bblk
//    pack, XCD-chunked remap, wave-local epilogue, atomicMax m_ws, tiny fc.
// ---------------------------------------------------------------------------

typedef __attribute__((ext_vector_type(8))) short short8;
typedef __attribute__((ext_vector_type(4))) float f32x4;

__device__ __forceinline__ unsigned short f2b(float f) {
    union { float f; unsigned u; } un;
    un.f = f;
    unsigned u = un.u;
    return (unsigned short)((u + 0x7FFFu + ((u >> 16) & 1u)) >> 16);  // RNE
}

__device__ __forceinline__ void gll4(const int* g, void* l) {
    __builtin_amdgcn_global_load_lds(
        (const __attribute__((address_space(1))) void*)g,
        (__attribute__((address_space(3))) void*)l, 4, 0, 0);
}

#define KT_COUNT 125                              // K = 4000 = 125 * 32
#define WS_BBLK_BYTES (KT_COUNT * 256 * 32 * 2)   // 2,048,000 B bf16 weights
#define WS_MWS_OFF WS_BBLK_BYTES                  // 8*128 f32 max accumulator

// Pack W1,W2 (fp32 [128][8][500]) -> bf16 Bblk[kt][c][g*8+ch], columns
// INTERLEAVED: c = grp*32+s; s<16 -> W1[grp*16+s], else W2[grp*16+s-16].
// Thread u owns (kt, c): reads 8 float4 (contiguous k), writes 64B
// contiguous. Also zero-inits m_ws.
__global__ __launch_bounds__(256) void prep_weights(
        const float* __restrict__ W1, const float* __restrict__ W2,
        unsigned short* __restrict__ Bblk, float* __restrict__ m_ws) {
    int u  = blockIdx.x * 256 + threadIdx.x;      // 0..31999
    int kt = u >> 8;                              // 0..124
    int c  = u & 255;
    int grp = c >> 5, s = c & 31;
    const float* W = (s < 16) ? W1 : W2;
    int oo = grp * 16 + (s & 15);                 // 0..127
    unsigned short v[4][8];
#pragma unroll
    for (int ch = 0; ch < 8; ++ch) {
        float4 w4 = *(const float4*)&W[oo * 4000 + ch * 500 + kt * 4];
        v[0][ch] = f2b(w4.x); v[1][ch] = f2b(w4.y);
        v[2][ch] = f2b(w4.z); v[3][ch] = f2b(w4.w);
    }
#pragma unroll
    for (int g = 0; g < 4; ++g) {
        uint4 pack;
        pack.x = (unsigned)v[g][0] | ((unsigned)v[g][1] << 16);
        pack.y = (unsigned)v[g][2] | ((unsigned)v[g][3] << 16);
        pack.z = (unsigned)v[g][4] | ((unsigned)v[g][5] << 16);
        pack.w = (unsigned)v[g][6] | ((unsigned)v[g][7] << 16);
        *(uint4*)&Bblk[u * 32 + g * 8] = pack;
    }
    if (blockIdx.x < 4) m_ws[blockIdx.x * 256 + threadIdx.x] = 0.f;
}

// Main fused kernel: 1000 blocks x 64 threads (one wave). Work item
// w = mt*4 + nq: rows mt*64..+63, interleaved cols nq*64..+63.
__global__ __launch_bounds__(64, 1) void malconv_main(
        const int* __restrict__ x, const float* __restrict__ emb,
        const float* __restrict__ b1, const float* __restrict__ b2,
        const unsigned short* __restrict__ Bblk, float* __restrict__ m_ws) {
    __shared__ __align__(16) unsigned short embb[257 * 8];  // bf16 emb rows
    __shared__ __align__(16) int xs[2][32][64];             // x stage: [pos][row]

    const int t = threadIdx.x;
    for (int e = t; e < 257 * 8; e += 64) embb[e] = f2b(emb[e]);

    // XCD-chunked remap: the 4 nq tiles of an m-tile sit 8 apart in
    // blockIdx -> same XCD under round-robin dispatch -> x/Bblk L2 reuse.
    const int w  = (blockIdx.x & 7) * 125 + (blockIdx.x >> 3);
    const int mt = w >> 2, nq = w & 3;
    const int m0 = mt * 64;

    const int quad = t >> 4, l16 = t & 15;

    // B fragment base: interleaved col = nq*64 + ni*16 + l16, 32 shorts/col
    // per kt, k-group = quad.
    const unsigned short* bbase = Bblk + (nq * 64 + l16) * 32 + quad * 8;

    // staging source: lane t covers row m0+t.
    const int* xrow = x + (m0 + t) * 500;

    // Stage super-phase Sn (positions Sn*32..+31) into xs[Sn&1]:
    // instr p: lane l -> src x[(m0+l)*500 + pos], dest xs[b][p][l] (lane-
    // linear 256B). Async: no dest VGPR -> the compiler cannot sink it.
    auto stage = [&](int Sn) {
        int* dst0 = &xs[Sn & 1][0][0];
#pragma unroll
        for (int p = 0; p < 32; ++p) {
            int pe = Sn * 32 + p;
            if (pe > 499) pe = 499;               // tail clamp (S=15)
            gll4(xrow + pe, (void*)(dst0 + p * 64));
        }
    };

    f32x4 acc[4][4];
#pragma unroll
    for (int mi = 0; mi < 4; ++mi)
#pragma unroll
        for (int ni = 0; ni < 4; ++ni) {
            f32x4 z = {0.f, 0.f, 0.f, 0.f};
            acc[mi][ni] = z;
        }

    stage(0);
    __syncthreads();   // embb + xs[0] ready

    // B prefetch: zero-copy even/odd sets (bA = next even kt, bB = next odd).
    short8 bA[4], bB[4];
#pragma unroll
    for (int ni = 0; ni < 4; ++ni) {
        bA[ni] = *(const short8*)(bbase + 0 * 8192 + ni * 512);
        bB[ni] = *(const short8*)(bbase + 1 * 8192 + ni * 512);
    }

    // One kt: xs-read (4x b32) -> embb gather (4x b128) -> 16 MFMA -> refill
    // this parity's B set with kt+2. Fully unrolled per super-phase: SSA
    // renaming lets the scheduler overlap kt+1's LDS reads with kt's MFMAs.
    auto step = [&](int kt, int kl, short8 (&B)[4], int cur) {
        int xv[4];
        short8 af[4];
#pragma unroll
        for (int mi = 0; mi < 4; ++mi)
            xv[mi] = xs[cur][kl * 4 + quad][mi * 16 + l16];
#pragma unroll
        for (int mi = 0; mi < 4; ++mi)
            af[mi] = *(const short8*)&embb[xv[mi] * 8];
#pragma unroll
        for (int mi = 0; mi < 4; ++mi)
#pragma unroll
            for (int ni = 0; ni < 4; ++ni)
                acc[mi][ni] = __builtin_amdgcn_mfma_f32_16x16x32_bf16(
                    af[mi], B[ni], acc[mi][ni], 0, 0, 0);
        const int ktn = (kt + 2 < KT_COUNT) ? kt + 2 : KT_COUNT - 1;
#pragma unroll
        for (int ni = 0; ni < 4; ++ni)
            B[ni] = *(const short8*)(bbase + ktn * 8192 + ni * 512);
    };

    // 15 full super-phases (kt 0..119) + 5-kt tail (kt 120..124).
    for (int S = 0; S < 15; ++S) {
        stage(S + 1);                 // in flight during this super-phase
        const int cur = S & 1;
#pragma unroll
        for (int kp = 0; kp < 4; ++kp) {
            step(S * 8 + kp * 2,     kp * 2,     bA, cur);
            step(S * 8 + kp * 2 + 1, kp * 2 + 1, bB, cur);
        }
        __syncthreads();              // drain stage(S+1), release xs[cur]
    }
    step(120, 0, bA, 1);
    step(121, 1, bB, 1);
    step(122, 2, bA, 1);
    step(123, 3, bB, 1);
    step(124, 4, bA, 1);

    // ---- wave-local epilogue: GLU + relu + segmented max ----
    // pair p: g1 = acc[mi][2p] (W1 out j), g2 = acc[mi][2p+1] (W2 out j),
    // j = nq*32 + p*16 + l16.
    const int b0i = m0 / 2000;
    const int bsplit = (b0i + 1) * 2000;          // first patch of next batch
    const bool crosses = (m0 + 63) >= bsplit;
#pragma unroll
    for (int p = 0; p < 2; ++p) {
        const int j = nq * 32 + p * 16 + l16;
        const float bb1 = b1[j], bb2 = b2[j];
        float mx0 = 0.f, mx1 = 0.f;               // h >= 0 always
#pragma unroll
        for (int mi = 0; mi < 4; ++mi)
#pragma unroll
            for (int r = 0; r < 4; ++r) {
                int row = m0 + mi * 16 + quad * 4 + r;
                float g1 = acc[mi][2 * p][r] + bb1;
                float g2 = acc[mi][2 * p + 1][r] + bb2;
                float h = fmaxf(g1 / (1.f + __expf(-g2)), 0.f);
                if (row >= bsplit) mx1 = fmaxf(mx1, h);
                else               mx0 = fmaxf(mx0, h);
            }
        // reduce over quad (lanes with same l16)
        mx0 = fmaxf(mx0, __shfl_xor(mx0, 16));
        mx0 = fmaxf(mx0, __shfl_xor(mx0, 32));
        mx1 = fmaxf(mx1, __shfl_xor(mx1, 16));
        mx1 = fmaxf(mx1, __shfl_xor(mx1, 32));
        if (quad == 0) {
            // nonneg floats: int compare == float compare
            atomicMax((int*)&m_ws[b0i * 128 + j], __float_as_int(mx0));
            if (crosses)
                atomicMax((int*)&m_ws[(b0i + 1) * 128 + j], __float_as_int(mx1));
        }
    }
}

// out[b][j] = sum_o m_ws[b][o] * fcW[j][o] + fcb[j]   (16 outputs)
__global__ void fc_kernel(const float* __restrict__ m_ws,
                          const float* __restrict__ fcW,
                          const float* __restrict__ fcb,
                          float* __restrict__ out) {
    int t = threadIdx.x;
    if (t < 16) {
        int b = t >> 1, j = t & 1;
        float s = 0.f;
        for (int o = 0; o < 128; ++o) s += m_ws[b * 128 + o] * fcW[j * 128 + o];
        out[t] = s + fcb[j];
    }
}

extern "C" void kernel_launch(void* const* d_in, const int* in_sizes, int n_in,
                              void* d_out, int out_size, void* d_ws, size_t ws_size,
                              hipStream_t stream) {
    const int*   x   = (const int*)d_in[0];     // [8, 1e6] values 0..256
    const float* emb = (const float*)d_in[1];   // [257, 8]
    const float* W1  = (const float*)d_in[2];   // [128, 8, 500]
    const float* b1  = (const float*)d_in[3];   // [128]
    const float* W2  = (const float*)d_in[4];   // [128, 8, 500]
    const float* b2  = (const float*)d_in[5];   // [128]
    const float* fcW = (const float*)d_in[6];   // [2, 128]
    const float* fcb = (const float*)d_in[7];   // [2]
    float* out = (float*)d_out;                 // [8, 2]

    unsigned short* Bblk = (unsigned short*)d_ws;
    float* m_ws = (float*)((char*)d_ws + WS_MWS_OFF);

    prep_weights<<<125, 256, 0, stream>>>(W1, W2, Bblk, m_ws);
    malconv_main<<<1000, 64, 0, stream>>>(x, emb, b1, b2, Bblk, m_ws);
    fc_kernel<<<1, 64, 0, stream>>>(m_ws, fcW, fcb, out);
}